// Round 3
// baseline (1328.880 us; speedup 1.0000x reference)
//
#include <hip/hip_runtime.h>
#include <hip/hip_bf16.h>

#define B_TOK 4096
#define DIM   2048
#define HID   4096
#define NEXP  8
#define CAP   4352   /* 4096 + BM slack for padding */

#define BM 256
#define BN 256
#define BK 64        /* bf16 elements per K tile; 2 K-halves of 32, dbuf */
#define KIT (DIM / BK)   /* 32, even */

typedef short  bf16x8 __attribute__((ext_vector_type(8)));
typedef unsigned short us16x8 __attribute__((ext_vector_type(8)));
typedef float  f32x4  __attribute__((ext_vector_type(4)));

__device__ __forceinline__ unsigned short f2bf(float f) {
    unsigned u = __builtin_bit_cast(unsigned, f);
    u += 0x7fffu + ((u >> 16) & 1u);          // round-to-nearest-even
    return (unsigned short)(u >> 16);
}

// async global -> LDS, 16 B per lane, LDS dest = wave-uniform base + lane*16
__device__ __forceinline__ void async_copy16(const void* g, void* l) {
    __builtin_amdgcn_global_load_lds(
        (const __attribute__((address_space(1))) unsigned*)g,
        (__attribute__((address_space(3))) unsigned*)l, 16, 0, 0);
}

// ---------------------------------------------------------------------------
// fp32 -> bf16 stream cast (expert_W; x cast is fused into gating)
// ---------------------------------------------------------------------------
__global__ __launch_bounds__(256) void cvt_kernel(
    const float* __restrict__ src, unsigned short* __restrict__ dst, long n) {
    long i = ((long)blockIdx.x * 256 + threadIdx.x) * 8;
    if (i >= n) return;
    float4 v0 = *(const float4*)(src + i);
    float4 v1 = *(const float4*)(src + i + 4);
    us16x8 o = { f2bf(v0.x), f2bf(v0.y), f2bf(v0.z), f2bf(v0.w),
                 f2bf(v1.x), f2bf(v1.y), f2bf(v1.z), f2bf(v1.w) };
    *(us16x8*)(dst + i) = o;
}

// ---------------------------------------------------------------------------
// c[n][e] = dot(emb[n], gate_W[e][D:2D]) + gate_b[e]   (24 waves total)
// ---------------------------------------------------------------------------
__global__ __launch_bounds__(256) void compute_c_kernel(
    const float* __restrict__ emb, const float* __restrict__ gate_W,
    const float* __restrict__ gate_b, float* __restrict__ cbuf) {
    int wave = (blockIdx.x * blockDim.x + threadIdx.x) >> 6;
    int lane = threadIdx.x & 63;
    if (wave >= 24) return;
    int n = wave >> 3, e = wave & 7;
    const float4* er = (const float4*)(emb + (size_t)n * DIM);
    const float4* wr = (const float4*)(gate_W + (size_t)e * 2 * DIM + DIM);
    float acc = 0.f;
    for (int c = lane; c < DIM / 4; c += 64) {
        float4 a = er[c], b = wr[c];
        acc += a.x * b.x + a.y * b.y + a.z * b.z + a.w * b.w;
    }
    #pragma unroll
    for (int off = 32; off; off >>= 1) acc += __shfl_down(acc, off, 64);
    if (lane == 0) cbuf[n * 8 + e] = acc + gate_b[e];
}

// ---------------------------------------------------------------------------
// Gating: one wave per token, fp32 (topk_idx must be exact). Also converts
// the token row to bf16 (fused x-cast). Writes expert dispatch lists with
// rank (0 = top-1 slot, 1 = top-2 slot) and per-token combine metadata.
// ---------------------------------------------------------------------------
__global__ __launch_bounds__(256) void gating_kernel(
    const float* __restrict__ x, const int* __restrict__ labels,
    const float* __restrict__ gate_W, const float* __restrict__ cbuf,
    int* __restrict__ counts, int* __restrict__ tlist, int* __restrict__ rlist,
    float* __restrict__ wA, float* __restrict__ wB,
    int* __restrict__ eA, int* __restrict__ eB,
    unsigned short* __restrict__ xb, float* __restrict__ out_idx) {
    int wave = threadIdx.x >> 6, lane = threadIdx.x & 63;
    int b = blockIdx.x * 4 + wave;
    const float4* xr  = (const float4*)(x + (size_t)b * DIM);
    const float4* gw4 = (const float4*)gate_W;
    unsigned short* xo = xb + (size_t)b * DIM;
    float acc[8] = {0.f, 0.f, 0.f, 0.f, 0.f, 0.f, 0.f, 0.f};
    for (int c = lane; c < DIM / 4; c += 64) {
        float4 xv = xr[c];
        ushort4 xc = { f2bf(xv.x), f2bf(xv.y), f2bf(xv.z), f2bf(xv.w) };
        *(ushort4*)(xo + 4 * c) = xc;
        #pragma unroll
        for (int e = 0; e < 8; ++e) {
            float4 wv = gw4[e * (2 * DIM / 4) + c];
            acc[e] += xv.x * wv.x + xv.y * wv.y + xv.z * wv.z + xv.w * wv.w;
        }
    }
    #pragma unroll
    for (int off = 32; off; off >>= 1) {
        #pragma unroll
        for (int e = 0; e < 8; ++e) acc[e] += __shfl_down(acc[e], off, 64);
    }
    if (lane == 0) {
        int lbl = labels[b];
        float lg[8];
        #pragma unroll
        for (int e = 0; e < 8; ++e) lg[e] = acc[e] + cbuf[lbl * 8 + e];
        int e0 = 0; float t0 = lg[0];
        #pragma unroll
        for (int e = 1; e < 8; ++e) if (lg[e] > t0) { t0 = lg[e]; e0 = e; }
        int e1 = -1; float t1 = -1e30f;
        #pragma unroll
        for (int e = 0; e < 8; ++e)
            if (e != e0 && lg[e] > t1) { t1 = lg[e]; e1 = e; }
        float w0 = 1.f / (1.f + __expf(t1 - t0));
        float w1 = 1.f - w0;
        int p0 = atomicAdd(&counts[e0], 1);
        int p1 = atomicAdd(&counts[e1], 1);
        tlist[e0 * CAP + p0] = b; rlist[e0 * CAP + p0] = 0;
        tlist[e1 * CAP + p1] = b; rlist[e1 * CAP + p1] = 1;
        wA[b] = w0; wB[b] = w1; eA[b] = e0; eB[b] = e1;
        out_idx[2 * b]     = (float)e0;
        out_idx[2 * b + 1] = (float)e1;
    }
}

// ---------------------------------------------------------------------------
// Pad each expert list to a multiple of BM: token 0, rank 2 (-> trash row).
// ---------------------------------------------------------------------------
__global__ void pad_kernel(const int* __restrict__ counts,
                           int* __restrict__ tlist, int* __restrict__ rlist) {
    int e = blockIdx.x, c = counts[e];
    int padded = (c + BM - 1) & ~(BM - 1);
    int i = c + threadIdx.x;
    if (i < padded) { tlist[e * CAP + i] = 0; rlist[e * CAP + i] = 2; }
}

// ---------------------------------------------------------------------------
// Grouped expert GEMM — 256x256 tile, BK=64, 8 waves (2M x 4N, 128x64 each),
// 8-phase schedule with counted vmcnt (T3+T4) + setprio (T5) on top of the
// R2-verified zero-conflict LDS swizzle (T2).
//
// LDS per operand: [2 buf][2 ks][256 rows][32 k] bf16 (64 B rows). K-half
// regions are contiguous -> global_load_lds stays linear. Swizzle (verified
// 0 conflicts in R2): phys 16B-slot = logical_slot ^ ((row>>1)&3), applied
// as pre-swizzled global source + swizzled ds_read (same involution).
//
// Per K-tile t (buf = t&1): 4 phases (mh in {0,1} x ks in {0,1}), 16 MFMA
// each; phase p stages one K-half of tile t+1 into buf^1 (2 loads/thread):
//   P1(mh0,ks0,+loadB): stage A-K0(t+1)
//   P2(mh1,ks0):        stage B-K0(t+1), then vmcnt(4) before barrier
//   P3(mh0,ks1,+loadB): stage A-K1(t+1)
//   P4(mh1,ks1):        stage B-K1(t+1), then vmcnt(4) before barrier
// FIFO queue at each wait = 8 loads; vmcnt(4) releases exactly the two
// K-halves the next two phases read; 4 loads always stay in flight (no
// drain-to-0 until the tail tile).
// ---------------------------------------------------------------------------
#define STAGE_A(BUF, KS, KT) do {                                        \
    const int _off = (KT) * BK + (KS) * 32;                              \
    async_copy16(gA0 + _off, &Ab[BUF][KS][ldsA0]);                       \
    async_copy16(gA1 + _off, &Ab[BUF][KS][ldsA1]);                       \
} while (0)

#define STAGE_B(BUF, KS, KT) do {                                        \
    const int _off = (KT) * BK + (KS) * 32;                              \
    async_copy16(gB0 + _off, &Bb[BUF][KS][ldsA0]);                       \
    async_copy16(gB1 + _off, &Bb[BUF][KS][ldsA1]);                       \
} while (0)

// WAITN: 4 = counted steady-state wait, 0 = tail drain, -1 = none
#define PHASE(BUF, MH, KS, LOADB, STAGE_STMT, WAITN) do {                \
    const unsigned short* _As = Ab[BUF][KS];                             \
    const unsigned short* _Bs = Bb[BUF][KS];                             \
    bf16x8 _a[4];                                                        \
    _Pragma("unroll")                                                    \
    for (int fi = 0; fi < 4; ++fi)                                       \
        _a[fi] = *(const bf16x8*)                                        \
            &_As[(wm * 128 + (MH) * 64 + fi * 16 + r) * 32 + fsw];       \
    if (LOADB) {                                                         \
        _Pragma("unroll")                                                \
        for (int nf = 0; nf < 4; ++nf)                                   \
            bfr[nf] = *(const bf16x8*)                                   \
                &_Bs[(wn * 64 + nf * 16 + r) * 32 + fsw];                \
    }                                                                    \
    STAGE_STMT;                                                          \
    asm volatile("" ::: "memory");                                       \
    __builtin_amdgcn_s_barrier();                                        \
    __builtin_amdgcn_sched_barrier(0);                                   \
    __builtin_amdgcn_s_setprio(1);                                       \
    _Pragma("unroll")                                                    \
    for (int fi = 0; fi < 4; ++fi)                                       \
        _Pragma("unroll")                                                \
        for (int nf = 0; nf < 4; ++nf)                                   \
            acc[(MH) * 4 + fi][nf] =                                     \
                __builtin_amdgcn_mfma_f32_16x16x32_bf16(                 \
                    _a[fi], bfr[nf], acc[(MH) * 4 + fi][nf], 0, 0, 0);   \
    __builtin_amdgcn_s_setprio(0);                                       \
    if ((WAITN) == 4)      asm volatile("s_waitcnt vmcnt(4)" ::: "memory"); \
    else if ((WAITN) == 0) asm volatile("s_waitcnt vmcnt(0)" ::: "memory"); \
    else                   asm volatile("" ::: "memory");                \
    __builtin_amdgcn_s_barrier();                                        \
    __builtin_amdgcn_sched_barrier(0);                                   \
} while (0)

__global__ __launch_bounds__(512, 2) void moe_gemm_kernel(
    const unsigned short* __restrict__ xb, const unsigned short* __restrict__ Wb,
    const int* __restrict__ counts, const int* __restrict__ tlist,
    const int* __restrict__ rlist,
    float* __restrict__ out0, float* __restrict__ y1, float* __restrict__ trash) {
    const int e  = blockIdx.z;
    const int m0 = blockIdx.y * BM;
    if (m0 >= counts[e]) return;
    const int n0 = blockIdx.x * BN;

    __shared__ unsigned short Ab[2][2][256 * 32];   // 16 KB per [buf][ks]
    __shared__ unsigned short Bb[2][2][256 * 32];
    __shared__ int toks[BM];
    __shared__ unsigned long long rowp[BM];

    const int t = threadIdx.x;
    if (t < BM) {
        int tok = tlist[e * CAP + m0 + t];
        int rk  = rlist[e * CAP + m0 + t];
        toks[t] = tok;
        float* p = (rk == 0) ? out0 + (size_t)tok * HID
                 : (rk == 1) ? y1   + (size_t)tok * HID
                             : trash;
        rowp[t] = (unsigned long long)p;
    }
    __syncthreads();   // full drain once, before the pipeline starts

    const int lane = t & 63, wv = t >> 6;
    const int r = lane & 15, quad = lane >> 4;
    const int wm = wv >> 2, wn = wv & 3;
    const int fsw = (quad ^ ((r >> 1) & 3)) * 8;   // swizzled elem-in-row

    // Staging: per K-half, 1024 16B chunks; thread covers chunks t and
    // t+512. chunk c -> row = c>>2, phys slot = c&3, logical slot =
    // phys ^ ((row>>1)&3); source element = row_base + lslot*8.
    const unsigned short *gA0, *gA1, *gB0, *gB1;
    int ldsA0, ldsA1;
    {
        int c0 = t,      row0 = c0 >> 2, ls0 = (c0 & 3) ^ ((row0 >> 1) & 3);
        int c1 = t + 512, row1 = c1 >> 2, ls1 = (c1 & 3) ^ ((row1 >> 1) & 3);
        gA0 = xb + (size_t)toks[row0] * DIM + ls0 * 8;
        gA1 = xb + (size_t)toks[row1] * DIM + ls1 * 8;
        gB0 = Wb + ((size_t)e * HID + n0 + row0) * DIM + ls0 * 8;
        gB1 = Wb + ((size_t)e * HID + n0 + row1) * DIM + ls1 * 8;
        ldsA0 = (wv * 64) * 8;            // wave-uniform chunk base (elems)
        ldsA1 = (512 + wv * 64) * 8;
    }

    f32x4 acc[8][4] = {};
    bf16x8 bfr[4];

    // prologue: all 4 K-halves of tile 0; release K0 halves, keep K1 in flight
    STAGE_A(0, 0, 0); STAGE_B(0, 0, 0); STAGE_A(0, 1, 0); STAGE_B(0, 1, 0);
    asm volatile("s_waitcnt vmcnt(4)" ::: "memory");
    __builtin_amdgcn_s_barrier();
    __builtin_amdgcn_sched_barrier(0);

    for (int k2 = 0; k2 < KIT; k2 += 2) {
        {   // tile k2 (buf 0); prefetch tile k2+1 into buf 1 (always exists)
            const int nt = k2 + 1;
            PHASE(0, 0, 0, 1, STAGE_A(1, 0, nt), -1);
            PHASE(0, 1, 0, 0, STAGE_B(1, 0, nt),  4);
            PHASE(0, 0, 1, 1, STAGE_A(1, 1, nt), -1);
            PHASE(0, 1, 1, 0, STAGE_B(1, 1, nt),  4);
        }
        if (k2 + 2 < KIT) {   // tile k2+1 (buf 1); prefetch k2+2 into buf 0
            const int nt = k2 + 2;
            PHASE(1, 0, 0, 1, STAGE_A(0, 0, nt), -1);
            PHASE(1, 1, 0, 0, STAGE_B(0, 0, nt),  4);
            PHASE(1, 0, 1, 1, STAGE_A(0, 1, nt), -1);
            PHASE(1, 1, 1, 0, STAGE_B(0, 1, nt),  4);
        } else {              // tail tile: no prefetch; drain K1 before use
            PHASE(1, 0, 0, 1, ((void)0), -1);
            PHASE(1, 1, 0, 0, ((void)0),  0);
            PHASE(1, 0, 1, 1, ((void)0), -1);
            PHASE(1, 1, 1, 0, ((void)0), -1);
        }
    }

    // Epilogue: plain stores via per-row destination pointers.
    #pragma unroll
    for (int nf = 0; nf < 4; ++nf) {
        int col = n0 + wn * 64 + nf * 16 + r;
        #pragma unroll
        for (int mi = 0; mi < 8; ++mi) {
            int rowb = wm * 128 + mi * 16 + quad * 4;
            #pragma unroll
            for (int r4 = 0; r4 < 4; ++r4) {
                float* dst = (float*)rowp[rowb + r4];
                dst[col] = acc[mi][nf][r4];
            }
        }
    }
}

// ---------------------------------------------------------------------------
// out[b] = w0*(y0+bias[e0]) + w1*(y1+bias[e1]),  y0 read in-place from out.
// ---------------------------------------------------------------------------
__global__ __launch_bounds__(256) void combine_kernel(
    const float* __restrict__ y1, const float* __restrict__ eb,
    const float* __restrict__ wA, const float* __restrict__ wB,
    const int* __restrict__ eA, const int* __restrict__ eB,
    float* __restrict__ out) {
    int b = blockIdx.x;
    float w0 = wA[b], w1 = wB[b];
    int e0 = eA[b], e1 = eB[b];
    const float4* y0r = (const float4*)(out + (size_t)b * HID);
    const float4* y1r = (const float4*)(y1 + (size_t)b * HID);
    const float4* b0r = (const float4*)(eb + (size_t)e0 * HID);
    const float4* b1r = (const float4*)(eb + (size_t)e1 * HID);
    float4* o = (float4*)(out + (size_t)b * HID);
    for (int i = threadIdx.x; i < HID / 4; i += 256) {
        float4 a = y0r[i], c = y1r[i], u = b0r[i], v = b1r[i];
        float4 rs;
        rs.x = w0 * (a.x + u.x) + w1 * (c.x + v.x);
        rs.y = w0 * (a.y + u.y) + w1 * (c.y + v.y);
        rs.z = w0 * (a.z + u.z) + w1 * (c.z + v.z);
        rs.w = w0 * (a.w + u.w) + w1 * (c.w + v.w);
        o[i] = rs;
    }
}

// ---------------------------------------------------------------------------
extern "C" void kernel_launch(void* const* d_in, const int* in_sizes, int n_in,
                              void* d_out, int out_size, void* d_ws, size_t ws_size,
                              hipStream_t stream) {
    const float* x        = (const float*)d_in[0];
    const int*   labels   = (const int*)  d_in[1];
    const float* emb      = (const float*)d_in[2];
    const float* gate_W   = (const float*)d_in[3];
    const float* gate_b   = (const float*)d_in[4];
    const float* expert_W = (const float*)d_in[5];
    const float* expert_b = (const float*)d_in[6];
    float* out = (float*)d_out;

    char* ws = (char*)d_ws;
    int*   counts = (int*)ws;                                  // 32 B
    float* cbuf   = (float*)(ws + 256);                        // 96 B
    int*   tlist  = (int*)(ws + 512);                          // 139264 B
    int*   rlist  = (int*)(ws + 512 + 139264);                 // 139264 B
    float* wA     = (float*)(ws + 279040);                     // 16 KB each
    float* wB     = (float*)(ws + 295424);
    int*   eA     = (int*)  (ws + 311808);
    int*   eB     = (int*)  (ws + 328192);
    float* trash  = (float*)(ws + 344576);                     // 16 KB
    float* y1     = (float*)(ws + 360960);                     // 67 MB
    unsigned short* xb = (unsigned short*)(ws + 360960 + (size_t)B_TOK * HID * 4);
    unsigned short* Wb = xb + (size_t)B_TOK * DIM;             // 134 MB
    // total ws use ≈ 208.3 MiB

    hipMemsetAsync(counts, 0, 8 * sizeof(int), stream);

    cvt_kernel<<<(NEXP * HID * DIM) / (8 * 256), 256, 0, stream>>>(
        expert_W, Wb, (long)NEXP * HID * DIM);
    compute_c_kernel<<<6, 256, 0, stream>>>(emb, gate_W, gate_b, cbuf);
    gating_kernel<<<B_TOK / 4, 256, 0, stream>>>(
        x, labels, gate_W, cbuf, counts, tlist, rlist, wA, wB, eA, eB, xb,
        out + (size_t)B_TOK * HID);
    pad_kernel<<<NEXP, 256, 0, stream>>>(counts, tlist, rlist);
    moe_gemm_kernel<<<dim3(HID / BN, B_TOK / BM, NEXP), 512, 0, stream>>>(
        xb, Wb, counts, tlist, rlist, out, y1, trash);
    combine_kernel<<<B_TOK, 256, 0, stream>>>(
        y1, expert_b, wA, wB, eA, eB, out);
}

// Round 4
// 831.420 us; speedup vs baseline: 1.5983x; 1.5983x over previous
//
#include <hip/hip_runtime.h>
#include <hip/hip_bf16.h>

#define B_TOK 4096
#define DIM   2048
#define HID   4096
#define NEXP  8
#define CAP   4224   /* 4096 + BM slack for padding */

#define BM 128
#define BN 128
#define BK 32        /* bf16 elements per K stage (dbuf: 2 stages in LDS) */
#define KITER (DIM / BK)

typedef short  bf16x8 __attribute__((ext_vector_type(8)));
typedef unsigned short us16x8 __attribute__((ext_vector_type(8)));
typedef float  f32x4  __attribute__((ext_vector_type(4)));

__device__ __forceinline__ unsigned short f2bf(float f) {
    unsigned u = __builtin_bit_cast(unsigned, f);
    u += 0x7fffu + ((u >> 16) & 1u);          // round-to-nearest-even
    return (unsigned short)(u >> 16);
}

// async global -> LDS, 16 B per lane, LDS dest = wave-uniform base + lane*16
__device__ __forceinline__ void async_copy16(const void* g, void* l) {
    __builtin_amdgcn_global_load_lds(
        (const __attribute__((address_space(1))) unsigned*)g,
        (__attribute__((address_space(3))) unsigned*)l, 16, 0, 0);
}

// ---------------------------------------------------------------------------
// fp32 -> bf16 stream cast (expert_W; x cast is fused into gating)
// ---------------------------------------------------------------------------
__global__ __launch_bounds__(256) void cvt_kernel(
    const float* __restrict__ src, unsigned short* __restrict__ dst, long n) {
    long stride = (long)gridDim.x * 256 * 8;
    for (long i = ((long)blockIdx.x * 256 + threadIdx.x) * 8; i < n; i += stride) {
        float4 v0 = *(const float4*)(src + i);
        float4 v1 = *(const float4*)(src + i + 4);
        us16x8 o = { f2bf(v0.x), f2bf(v0.y), f2bf(v0.z), f2bf(v0.w),
                     f2bf(v1.x), f2bf(v1.y), f2bf(v1.z), f2bf(v1.w) };
        *(us16x8*)(dst + i) = o;
    }
}

// ---------------------------------------------------------------------------
// c[n][e] = dot(emb[n], gate_W[e][D:2D]) + gate_b[e]   (24 waves total)
// ---------------------------------------------------------------------------
__global__ __launch_bounds__(256) void compute_c_kernel(
    const float* __restrict__ emb, const float* __restrict__ gate_W,
    const float* __restrict__ gate_b, float* __restrict__ cbuf) {
    int wave = (blockIdx.x * blockDim.x + threadIdx.x) >> 6;
    int lane = threadIdx.x & 63;
    if (wave >= 24) return;
    int n = wave >> 3, e = wave & 7;
    const float4* er = (const float4*)(emb + (size_t)n * DIM);
    const float4* wr = (const float4*)(gate_W + (size_t)e * 2 * DIM + DIM);
    float acc = 0.f;
    for (int c = lane; c < DIM / 4; c += 64) {
        float4 a = er[c], b = wr[c];
        acc += a.x * b.x + a.y * b.y + a.z * b.z + a.w * b.w;
    }
    #pragma unroll
    for (int off = 32; off; off >>= 1) acc += __shfl_down(acc, off, 64);
    if (lane == 0) cbuf[n * 8 + e] = acc + gate_b[e];
}

// ---------------------------------------------------------------------------
// Gating: one wave per token, fp32 (topk_idx must be exact). Also converts
// the token row to bf16 (fused x-cast). Writes expert dispatch lists with
// rank (0 = top-1 slot, 1 = top-2 slot) and per-token combine weights.
// ---------------------------------------------------------------------------
__global__ __launch_bounds__(256) void gating_kernel(
    const float* __restrict__ x, const int* __restrict__ labels,
    const float* __restrict__ gate_W, const float* __restrict__ cbuf,
    int* __restrict__ counts, int* __restrict__ tlist, int* __restrict__ rlist,
    float* __restrict__ wA, float* __restrict__ wB,
    unsigned short* __restrict__ xb, float* __restrict__ out_idx) {
    int wave = threadIdx.x >> 6, lane = threadIdx.x & 63;
    int b = blockIdx.x * 4 + wave;
    const float4* xr  = (const float4*)(x + (size_t)b * DIM);
    const float4* gw4 = (const float4*)gate_W;
    unsigned short* xo = xb + (size_t)b * DIM;
    float acc[8] = {0.f, 0.f, 0.f, 0.f, 0.f, 0.f, 0.f, 0.f};
    for (int c = lane; c < DIM / 4; c += 64) {
        float4 xv = xr[c];
        ushort4 xc = { f2bf(xv.x), f2bf(xv.y), f2bf(xv.z), f2bf(xv.w) };
        *(ushort4*)(xo + 4 * c) = xc;
        #pragma unroll
        for (int e = 0; e < 8; ++e) {
            float4 wv = gw4[e * (2 * DIM / 4) + c];
            acc[e] += xv.x * wv.x + xv.y * wv.y + xv.z * wv.z + xv.w * wv.w;
        }
    }
    #pragma unroll
    for (int off = 32; off; off >>= 1) {
        #pragma unroll
        for (int e = 0; e < 8; ++e) acc[e] += __shfl_down(acc[e], off, 64);
    }
    if (lane == 0) {
        int lbl = labels[b];
        float lg[8];
        #pragma unroll
        for (int e = 0; e < 8; ++e) lg[e] = acc[e] + cbuf[lbl * 8 + e];
        int e0 = 0; float t0 = lg[0];
        #pragma unroll
        for (int e = 1; e < 8; ++e) if (lg[e] > t0) { t0 = lg[e]; e0 = e; }
        int e1 = -1; float t1 = -1e30f;
        #pragma unroll
        for (int e = 0; e < 8; ++e)
            if (e != e0 && lg[e] > t1) { t1 = lg[e]; e1 = e; }
        float w0 = 1.f / (1.f + __expf(t1 - t0));
        float w1 = 1.f - w0;
        int p0 = atomicAdd(&counts[e0], 1);
        int p1 = atomicAdd(&counts[e1], 1);
        tlist[e0 * CAP + p0] = b; rlist[e0 * CAP + p0] = 0;
        tlist[e1 * CAP + p1] = b; rlist[e1 * CAP + p1] = 1;
        wA[b] = w0; wB[b] = w1;
        out_idx[2 * b]     = (float)e0;
        out_idx[2 * b + 1] = (float)e1;
    }
}

// ---------------------------------------------------------------------------
// Pad each expert list to a multiple of BM: token 0, rank 2 (-> weight 0).
// ---------------------------------------------------------------------------
__global__ void pad_kernel(const int* __restrict__ counts,
                           int* __restrict__ tlist, int* __restrict__ rlist) {
    int e = blockIdx.x, c = counts[e];
    int padded = (c + BM - 1) & ~(BM - 1);
    int i = c + threadIdx.x;
    if (i < padded) { tlist[e * CAP + i] = 0; rlist[e * CAP + i] = 2; }
}

// ---------------------------------------------------------------------------
// Grouped expert GEMM — R2's proven inner loop (distance-1 double-buffered
// global_load_lds, BK=32, zero-conflict swizzle slot ^= (row>>1)&3),
// UNCHANGED. Epilogue now fuses the combine (R1-proven correctness):
// out[tok][col] += w * (acc + bias[e][col]) via atomicAdd; out pre-zeroed;
// pad rows (w==0) skipped. Bias folds exactly since w0+w1=1 per token.
// ---------------------------------------------------------------------------
__global__ __launch_bounds__(256, 4) void moe_gemm_kernel(
    const unsigned short* __restrict__ xb, const unsigned short* __restrict__ Wb,
    const int* __restrict__ counts, const int* __restrict__ tlist,
    const int* __restrict__ rlist, const float* __restrict__ wA,
    const float* __restrict__ wB, const float* __restrict__ eb,
    float* __restrict__ out) {
    const int e  = blockIdx.z;
    const int m0 = blockIdx.y * BM;
    if (m0 >= counts[e]) return;
    const int n0 = blockIdx.x * BN;

    __shared__ unsigned short As0[BM * BK], As1[BM * BK];   // 8 KB each
    __shared__ unsigned short Bs0[BN * BK], Bs1[BN * BK];
    __shared__ int   toks[BM];
    __shared__ float roww[BM];

    const int t = threadIdx.x;
    if (t < BM) {
        int tok = tlist[e * CAP + m0 + t];
        int rk  = rlist[e * CAP + m0 + t];
        toks[t] = tok;
        roww[t] = (rk == 0) ? wA[tok] : (rk == 1) ? wB[tok] : 0.f;
    }
    __syncthreads();

    const int lane = t & 63, wave = t >> 6;
    const int rowc = lane >> 2;                     // 0..15
    const int colg = lane & 3;
    const int gcol = ((colg ^ ((rowc >> 1) & 3)) * 8);  // swizzled K-group (elems)

    const unsigned short* gA[2];
    const unsigned short* gB[2];
    int ldsoff[2];
    #pragma unroll
    for (int j = 0; j < 2; ++j) {
        int row = wave * 32 + j * 16 + rowc;
        gA[j] = xb + (size_t)toks[row] * DIM + gcol;
        gB[j] = Wb + ((size_t)e * HID + n0 + row) * DIM + gcol;
        ldsoff[j] = (wave * 32 + j * 16) * BK;
    }

    const int wm = wave >> 1, wn = wave & 1;
    const int r = lane & 15, quad = lane >> 4;
    const int pg = ((quad ^ ((r >> 1) & 3)) * 8);   // physical group for frags

    f32x4 acc[4][4] = {};

    auto stage = [&](unsigned short* Ad, unsigned short* Bd, int kstep) {
        const int kc = kstep * BK;
        #pragma unroll
        for (int j = 0; j < 2; ++j) {
            async_copy16(gA[j] + kc, Ad + ldsoff[j]);
            async_copy16(gB[j] + kc, Bd + ldsoff[j]);
        }
    };
    auto compute = [&](const unsigned short* Ab, const unsigned short* Bb) {
        bf16x8 af[4], bfr[4];
        #pragma unroll
        for (int i = 0; i < 4; ++i) {
            af[i]  = *(const bf16x8*)&Ab[(wm * 64 + i * 16 + r) * BK + pg];
            bfr[i] = *(const bf16x8*)&Bb[(wn * 64 + i * 16 + r) * BK + pg];
        }
        #pragma unroll
        for (int im = 0; im < 4; ++im)
            #pragma unroll
            for (int in = 0; in < 4; ++in)
                acc[im][in] = __builtin_amdgcn_mfma_f32_16x16x32_bf16(
                    af[im], bfr[in], acc[im][in], 0, 0, 0);
    };

    stage(As0, Bs0, 0);
    __syncthreads();
    for (int k2 = 0; k2 < KITER; k2 += 2) {
        stage(As1, Bs1, k2 + 1);          // prefetch next stage
        compute(As0, Bs0);                // covers the vmcnt drain below
        __syncthreads();
        if (k2 + 2 < KITER) stage(As0, Bs0, k2 + 2);
        compute(As1, Bs1);
        __syncthreads();
    }

    // Fused-combine epilogue: out[tok][col] += w * (acc + bias[e][col]).
    #pragma unroll
    for (int in = 0; in < 4; ++in) {
        int col = n0 + wn * 64 + in * 16 + r;
        float bc = eb[(size_t)e * HID + col];
        #pragma unroll
        for (int im = 0; im < 4; ++im) {
            int rowb = wm * 64 + im * 16 + quad * 4;
            #pragma unroll
            for (int r4 = 0; r4 < 4; ++r4) {
                float w = roww[rowb + r4];
                if (w != 0.f)
                    atomicAdd(out + (size_t)toks[rowb + r4] * HID + col,
                              w * (acc[im][in][r4] + bc));
            }
        }
    }
}

// ---------------------------------------------------------------------------
extern "C" void kernel_launch(void* const* d_in, const int* in_sizes, int n_in,
                              void* d_out, int out_size, void* d_ws, size_t ws_size,
                              hipStream_t stream) {
    const float* x        = (const float*)d_in[0];
    const int*   labels   = (const int*)  d_in[1];
    const float* emb      = (const float*)d_in[2];
    const float* gate_W   = (const float*)d_in[3];
    const float* gate_b   = (const float*)d_in[4];
    const float* expert_W = (const float*)d_in[5];
    const float* expert_b = (const float*)d_in[6];
    float* out = (float*)d_out;

    char* ws = (char*)d_ws;
    int*   counts = (int*)ws;                                  // 32 B
    float* cbuf   = (float*)(ws + 256);                        // 96 B
    int*   tlist  = (int*)(ws + 512);                          // 135168 B
    int*   rlist  = (int*)(ws + 512 + 135168);                 // 135168 B
    float* wA     = (float*)(ws + 270848);                     // 16 KB each
    float* wB     = (float*)(ws + 287232);
    unsigned short* xb = (unsigned short*)(ws + 303616);       // 16 MB
    unsigned short* Wb = xb + (size_t)B_TOK * DIM;             // 134 MB
    // total ws use ≈ 151.3 MiB

    hipMemsetAsync(counts, 0, 8 * sizeof(int), stream);
    hipMemsetAsync(out, 0, (size_t)B_TOK * HID * sizeof(float), stream);

    cvt_kernel<<<4096, 256, 0, stream>>>(
        expert_W, Wb, (long)NEXP * HID * DIM);
    compute_c_kernel<<<6, 256, 0, stream>>>(emb, gate_W, gate_b, cbuf);
    gating_kernel<<<B_TOK / 4, 256, 0, stream>>>(
        x, labels, gate_W, cbuf, counts, tlist, rlist, wA, wB, xb,
        out + (size_t)B_TOK * HID);
    pad_kernel<<<NEXP, BM, 0, stream>>>(counts, tlist, rlist);
    moe_gemm_kernel<<<dim3(HID / BN, B_TOK / BM, NEXP), 256, 0, stream>>>(
        xb, Wb, counts, tlist, rlist, wA, wB, expert_b, out);
}

// Round 5
// 796.043 us; speedup vs baseline: 1.6694x; 1.0444x over previous
//
#include <hip/hip_runtime.h>
#include <hip/hip_bf16.h>

#define B_TOK 4096
#define DIM   2048
#define HID   4096
#define NEXP  8
#define CAP   4352   /* 4096 + BM slack for padding */

#define BM 256
#define BN 256
#define BK 64            /* bf16 elems per K tile: 2 K-halves of 32, dbuf */
#define KIT (DIM / BK)   /* 32 */

typedef short  bf16x8 __attribute__((ext_vector_type(8)));
typedef unsigned short us16x8 __attribute__((ext_vector_type(8)));
typedef float  f32x4  __attribute__((ext_vector_type(4)));

__device__ __forceinline__ unsigned short f2bf(float f) {
    unsigned u = __builtin_bit_cast(unsigned, f);
    u += 0x7fffu + ((u >> 16) & 1u);          // round-to-nearest-even
    return (unsigned short)(u >> 16);
}

// async global -> LDS, 16 B per lane, LDS dest = wave-uniform base + lane*16
__device__ __forceinline__ void async_copy16(const void* g, void* l) {
    __builtin_amdgcn_global_load_lds(
        (const __attribute__((address_space(1))) unsigned*)g,
        (__attribute__((address_space(3))) unsigned*)l, 16, 0, 0);
}

// ---------------------------------------------------------------------------
// fp32 -> bf16 stream cast (expert_W; x cast is fused into gating)
// ---------------------------------------------------------------------------
__global__ __launch_bounds__(256) void cvt_kernel(
    const float* __restrict__ src, unsigned short* __restrict__ dst, long n) {
    long stride = (long)gridDim.x * 256 * 8;
    for (long i = ((long)blockIdx.x * 256 + threadIdx.x) * 8; i < n; i += stride) {
        float4 v0 = *(const float4*)(src + i);
        float4 v1 = *(const float4*)(src + i + 4);
        us16x8 o = { f2bf(v0.x), f2bf(v0.y), f2bf(v0.z), f2bf(v0.w),
                     f2bf(v1.x), f2bf(v1.y), f2bf(v1.z), f2bf(v1.w) };
        *(us16x8*)(dst + i) = o;
    }
}

// ---------------------------------------------------------------------------
// c[n][e] = dot(emb[n], gate_W[e][D:2D]) + gate_b[e]   (24 waves total)
// ---------------------------------------------------------------------------
__global__ __launch_bounds__(256) void compute_c_kernel(
    const float* __restrict__ emb, const float* __restrict__ gate_W,
    const float* __restrict__ gate_b, float* __restrict__ cbuf) {
    int wave = (blockIdx.x * blockDim.x + threadIdx.x) >> 6;
    int lane = threadIdx.x & 63;
    if (wave >= 24) return;
    int n = wave >> 3, e = wave & 7;
    const float4* er = (const float4*)(emb + (size_t)n * DIM);
    const float4* wr = (const float4*)(gate_W + (size_t)e * 2 * DIM + DIM);
    float acc = 0.f;
    for (int c = lane; c < DIM / 4; c += 64) {
        float4 a = er[c], b = wr[c];
        acc += a.x * b.x + a.y * b.y + a.z * b.z + a.w * b.w;
    }
    #pragma unroll
    for (int off = 32; off; off >>= 1) acc += __shfl_down(acc, off, 64);
    if (lane == 0) cbuf[n * 8 + e] = acc + gate_b[e];
}

// ---------------------------------------------------------------------------
// Gating: one wave per token, fp32 (topk_idx must be exact). Also converts
// the token row to bf16 (fused x-cast). Writes expert dispatch lists with
// rank (0 = top-1 slot, 1 = top-2 slot) and per-token combine metadata.
// ---------------------------------------------------------------------------
__global__ __launch_bounds__(256) void gating_kernel(
    const float* __restrict__ x, const int* __restrict__ labels,
    const float* __restrict__ gate_W, const float* __restrict__ cbuf,
    int* __restrict__ counts, int* __restrict__ tlist, int* __restrict__ rlist,
    float* __restrict__ wA, float* __restrict__ wB,
    int* __restrict__ eA, int* __restrict__ eB,
    unsigned short* __restrict__ xb, float* __restrict__ out_idx) {
    int wave = threadIdx.x >> 6, lane = threadIdx.x & 63;
    int b = blockIdx.x * 4 + wave;
    const float4* xr  = (const float4*)(x + (size_t)b * DIM);
    const float4* gw4 = (const float4*)gate_W;
    unsigned short* xo = xb + (size_t)b * DIM;
    float acc[8] = {0.f, 0.f, 0.f, 0.f, 0.f, 0.f, 0.f, 0.f};
    for (int c = lane; c < DIM / 4; c += 64) {
        float4 xv = xr[c];
        ushort4 xc = { f2bf(xv.x), f2bf(xv.y), f2bf(xv.z), f2bf(xv.w) };
        *(ushort4*)(xo + 4 * c) = xc;
        #pragma unroll
        for (int e = 0; e < 8; ++e) {
            float4 wv = gw4[e * (2 * DIM / 4) + c];
            acc[e] += xv.x * wv.x + xv.y * wv.y + xv.z * wv.z + xv.w * wv.w;
        }
    }
    #pragma unroll
    for (int off = 32; off; off >>= 1) {
        #pragma unroll
        for (int e = 0; e < 8; ++e) acc[e] += __shfl_down(acc[e], off, 64);
    }
    if (lane == 0) {
        int lbl = labels[b];
        float lg[8];
        #pragma unroll
        for (int e = 0; e < 8; ++e) lg[e] = acc[e] + cbuf[lbl * 8 + e];
        int e0 = 0; float t0 = lg[0];
        #pragma unroll
        for (int e = 1; e < 8; ++e) if (lg[e] > t0) { t0 = lg[e]; e0 = e; }
        int e1 = -1; float t1 = -1e30f;
        #pragma unroll
        for (int e = 0; e < 8; ++e)
            if (e != e0 && lg[e] > t1) { t1 = lg[e]; e1 = e; }
        float w0 = 1.f / (1.f + __expf(t1 - t0));
        float w1 = 1.f - w0;
        int p0 = atomicAdd(&counts[e0], 1);
        int p1 = atomicAdd(&counts[e1], 1);
        tlist[e0 * CAP + p0] = b; rlist[e0 * CAP + p0] = 0;
        tlist[e1 * CAP + p1] = b; rlist[e1 * CAP + p1] = 1;
        wA[b] = w0; wB[b] = w1; eA[b] = e0; eB[b] = e1;
        out_idx[2 * b]     = (float)e0;
        out_idx[2 * b + 1] = (float)e1;
    }
}

// ---------------------------------------------------------------------------
// Pad each expert list to a multiple of BM: token 0, rank 2 (-> trash row).
// ---------------------------------------------------------------------------
__global__ void pad_kernel(const int* __restrict__ counts,
                           int* __restrict__ tlist, int* __restrict__ rlist) {
    int e = blockIdx.x, c = counts[e];
    int padded = (c + BM - 1) & ~(BM - 1);
    int i = c + threadIdx.x;
    if (i < padded) { tlist[e * CAP + i] = 0; rlist[e * CAP + i] = 2; }
}

// ---------------------------------------------------------------------------
// Grouped expert GEMM — 256x256 tile, BK=64, 8 waves (2M x 4N, 128x64/wave),
// 4-phase-per-K-tile schedule with counted vmcnt(4) (T3+T4), setprio (T5),
// on the R2-verified zero-conflict swizzle (T2: 64B rows, slot ^= (row>>1)&3,
// pre-swizzled source + swizzled ds_read). Schedule correctness was proven
// in R3 (passed); R3's regression was register SPILL (1.35 GB scratch
// writes, VGPR capped at 128 by launch_bounds(512,2)). Mitigations here:
//   - __launch_bounds__(512) with NO min-waves arg (no reg cap; occupancy
//     is LDS-bound at 1 block/CU regardless: 131 KB LDS)
//   - 32-bit staging offsets off uniform SGPR bases (saves 12 VGPRs)
//   - no cross-phase register state except acc (b-frags reloaded per phase)
// Epilogue: R2's plain stores (rank0->out, rank1->y1, pad->trash).
//
// vmcnt FIFO accounting (2 loads per stage call, per wave):
//   tile t phases: p1 stage A-ks0(t+1), p2 stage B-ks0(t+1) then vmcnt(4)
//   [releases A/B-ks1(t) read by p3/p4], p3 stage A-ks1(t+1), p4 stage
//   B-ks1(t+1) then vmcnt(4) [releases A/B-ks0(t+1) read by next p1/p2].
//   Queue never drains below 4 until the tail tile.
// ---------------------------------------------------------------------------
#define STAGE_A(NB, KS, KT) do {                                         \
    const int _kc = (KT) * BK + (KS) * 32;                               \
    async_copy16(xb + offA0 + _kc, &Ab[NB][KS][ldsc0]);                  \
    async_copy16(xb + offA1 + _kc, &Ab[NB][KS][ldsc1]);                  \
} while (0)

#define STAGE_B(NB, KS, KT) do {                                         \
    const int _kc = (KT) * BK + (KS) * 32;                               \
    async_copy16(Wbe + offB0 + _kc, &Bb[NB][KS][ldsc0]);                 \
    async_copy16(Wbe + offB1 + _kc, &Bb[NB][KS][ldsc1]);                 \
} while (0)

#define WAIT4 asm volatile("s_waitcnt vmcnt(4)" ::: "memory")
#define WAIT0 asm volatile("s_waitcnt vmcnt(0)" ::: "memory")
#define WAITX do {} while (0)

#define PHASE(BUF, MH, KS, STAGE_STMT, WAIT_STMT) do {                   \
    const unsigned short* _As = &Ab[BUF][KS][0];                         \
    const unsigned short* _Bs = &Bb[BUF][KS][0];                         \
    bf16x8 _a[4], _b[4];                                                 \
    _Pragma("unroll")                                                    \
    for (int fi = 0; fi < 4; ++fi)                                       \
        _a[fi] = *(const bf16x8*)&_As[aoff[MH][fi]];                     \
    _Pragma("unroll")                                                    \
    for (int nf = 0; nf < 4; ++nf)                                       \
        _b[nf] = *(const bf16x8*)&_Bs[boff[nf]];                         \
    STAGE_STMT;                                                          \
    __builtin_amdgcn_s_barrier();                                        \
    __builtin_amdgcn_sched_barrier(0);                                   \
    __builtin_amdgcn_s_setprio(1);                                       \
    _Pragma("unroll")                                                    \
    for (int fi = 0; fi < 4; ++fi)                                       \
        _Pragma("unroll")                                                \
        for (int nf = 0; nf < 4; ++nf)                                   \
            acc[(MH) * 4 + fi][nf] =                                     \
                __builtin_amdgcn_mfma_f32_16x16x32_bf16(                 \
                    _a[fi], _b[nf], acc[(MH) * 4 + fi][nf], 0, 0, 0);    \
    __builtin_amdgcn_s_setprio(0);                                       \
    WAIT_STMT;                                                           \
    __builtin_amdgcn_s_barrier();                                        \
    __builtin_amdgcn_sched_barrier(0);                                   \
} while (0)

__global__ __launch_bounds__(512) void moe_gemm_kernel(
    const unsigned short* __restrict__ xb, const unsigned short* __restrict__ Wb,
    const int* __restrict__ counts, const int* __restrict__ tlist,
    const int* __restrict__ rlist,
    float* __restrict__ out0, float* __restrict__ y1, float* __restrict__ trash) {
    const int e  = blockIdx.z;
    const int m0 = blockIdx.y * BM;
    if (m0 >= counts[e]) return;
    const int n0 = blockIdx.x * BN;

    __shared__ unsigned short Ab[2][2][256 * 32];   // 16 KB per [buf][ks]
    __shared__ unsigned short Bb[2][2][256 * 32];
    __shared__ int toks[BM];
    __shared__ unsigned long long rowp[BM];

    const int t = threadIdx.x;
    if (t < BM) {
        int tok = tlist[e * CAP + m0 + t];
        int rk  = rlist[e * CAP + m0 + t];
        toks[t] = tok;
        float* p = (rk == 0) ? out0 + (size_t)tok * HID
                 : (rk == 1) ? y1   + (size_t)tok * HID
                             : trash;
        rowp[t] = (unsigned long long)p;
    }
    __syncthreads();

    const int lane = t & 63, wv = t >> 6;
    const int r = lane & 15, quad = lane >> 4;
    const int wm = wv >> 2, wn = wv & 3;
    const int fsw = (quad ^ ((r >> 1) & 3)) * 8;   // swizzled elem-in-row

    // 32-bit staging offsets (bases xb / Wbe stay uniform in SGPRs).
    const unsigned short* Wbe = Wb + (size_t)e * HID * DIM;
    int offA0, offA1, offB0, offB1, ldsc0, ldsc1;
    {
        int c0 = t,       row0 = c0 >> 2, ls0 = (c0 & 3) ^ ((row0 >> 1) & 3);
        int c1 = t + 512, row1 = c1 >> 2, ls1 = (c1 & 3) ^ ((row1 >> 1) & 3);
        offA0 = toks[row0] * DIM + ls0 * 8;
        offA1 = toks[row1] * DIM + ls1 * 8;
        offB0 = (n0 + row0) * DIM + ls0 * 8;
        offB1 = (n0 + row1) * DIM + ls1 * 8;
        ldsc0 = (wv * 64) * 8;            // wave-uniform chunk base (elems)
        ldsc1 = (512 + wv * 64) * 8;
    }

    // Precomputed swizzled fragment offsets (elems).
    int aoff[2][4], boff[4];
    #pragma unroll
    for (int mh = 0; mh < 2; ++mh)
        #pragma unroll
        for (int fi = 0; fi < 4; ++fi)
            aoff[mh][fi] = (wm * 128 + mh * 64 + fi * 16 + r) * 32 + fsw;
    #pragma unroll
    for (int nf = 0; nf < 4; ++nf)
        boff[nf] = (wn * 64 + nf * 16 + r) * 32 + fsw;

    f32x4 acc[8][4] = {};

    // prologue: all 4 K-halves of tile 0; release ks0, keep ks1 in flight
    STAGE_A(0, 0, 0); STAGE_B(0, 0, 0); STAGE_A(0, 1, 0); STAGE_B(0, 1, 0);
    WAIT4;
    __builtin_amdgcn_s_barrier();
    __builtin_amdgcn_sched_barrier(0);

    for (int kt = 0; kt < KIT; ++kt) {
        const int buf = kt & 1, nb = buf ^ 1;
        if (kt + 1 < KIT) {
            const int nt = kt + 1;
            PHASE(buf, 0, 0, STAGE_A(nb, 0, nt), WAITX);
            PHASE(buf, 1, 0, STAGE_B(nb, 0, nt), WAIT4);
            PHASE(buf, 0, 1, STAGE_A(nb, 1, nt), WAITX);
            PHASE(buf, 1, 1, STAGE_B(nb, 1, nt), WAIT4);
        } else {       // tail tile: no prefetch; drain before ks1 reads
            PHASE(buf, 0, 0, WAITX, WAITX);
            PHASE(buf, 1, 0, WAITX, WAIT0);
            PHASE(buf, 0, 1, WAITX, WAITX);
            PHASE(buf, 1, 1, WAITX, WAITX);
        }
    }

    // Epilogue: plain stores via per-row destination pointers (R2 style).
    #pragma unroll
    for (int nf = 0; nf < 4; ++nf) {
        int col = n0 + wn * 64 + nf * 16 + r;
        #pragma unroll
        for (int mi = 0; mi < 8; ++mi) {
            int rowb = wm * 128 + mi * 16 + quad * 4;
            #pragma unroll
            for (int r4 = 0; r4 < 4; ++r4) {
                float* dst = (float*)rowp[rowb + r4];
                dst[col] = acc[mi][nf][r4];
            }
        }
    }
}

// ---------------------------------------------------------------------------
// out[b] = w0*(y0+bias[e0]) + w1*(y1+bias[e1]),  y0 read in-place from out.
// ---------------------------------------------------------------------------
__global__ __launch_bounds__(256) void combine_kernel(
    const float* __restrict__ y1, const float* __restrict__ eb,
    const float* __restrict__ wA, const float* __restrict__ wB,
    const int* __restrict__ eA, const int* __restrict__ eB,
    float* __restrict__ out) {
    int b = blockIdx.x;
    float w0 = wA[b], w1 = wB[b];
    int e0 = eA[b], e1 = eB[b];
    const float4* y0r = (const float4*)(out + (size_t)b * HID);
    const float4* y1r = (const float4*)(y1 + (size_t)b * HID);
    const float4* b0r = (const float4*)(eb + (size_t)e0 * HID);
    const float4* b1r = (const float4*)(eb + (size_t)e1 * HID);
    float4* o = (float4*)(out + (size_t)b * HID);
    for (int i = threadIdx.x; i < HID / 4; i += 256) {
        float4 a = y0r[i], c = y1r[i], u = b0r[i], v = b1r[i];
        float4 rs;
        rs.x = w0 * (a.x + u.x) + w1 * (c.x + v.x);
        rs.y = w0 * (a.y + u.y) + w1 * (c.y + v.y);
        rs.z = w0 * (a.z + u.z) + w1 * (c.z + v.z);
        rs.w = w0 * (a.w + u.w) + w1 * (c.w + v.w);
        o[i] = rs;
    }
}

// ---------------------------------------------------------------------------
extern "C" void kernel_launch(void* const* d_in, const int* in_sizes, int n_in,
                              void* d_out, int out_size, void* d_ws, size_t ws_size,
                              hipStream_t stream) {
    const float* x        = (const float*)d_in[0];
    const int*   labels   = (const int*)  d_in[1];
    const float* emb      = (const float*)d_in[2];
    const float* gate_W   = (const float*)d_in[3];
    const float* gate_b   = (const float*)d_in[4];
    const float* expert_W = (const float*)d_in[5];
    const float* expert_b = (const float*)d_in[6];
    float* out = (float*)d_out;

    char* ws = (char*)d_ws;
    int*   counts = (int*)ws;                                  // 32 B
    float* cbuf   = (float*)(ws + 256);                        // 96 B
    int*   tlist  = (int*)(ws + 512);                          // 139264 B
    int*   rlist  = (int*)(ws + 139776);                       // 139264 B
    float* wA     = (float*)(ws + 279040);                     // 16 KB each
    float* wB     = (float*)(ws + 295424);
    int*   eA     = (int*)  (ws + 311808);
    int*   eB     = (int*)  (ws + 328192);
    float* trash  = (float*)(ws + 344576);                     // 16 KB
    float* y1     = (float*)(ws + 360960);                     // 67 MB
    unsigned short* xb = (unsigned short*)(ws + 360960 + (size_t)B_TOK * HID * 4);
    unsigned short* Wb = xb + (size_t)B_TOK * DIM;             // 134 MB
    // total ws use ≈ 208.3 MiB

    hipMemsetAsync(counts, 0, 8 * sizeof(int), stream);

    cvt_kernel<<<4096, 256, 0, stream>>>(
        expert_W, Wb, (long)NEXP * HID * DIM);
    compute_c_kernel<<<6, 256, 0, stream>>>(emb, gate_W, gate_b, cbuf);
    gating_kernel<<<B_TOK / 4, 256, 0, stream>>>(
        x, labels, gate_W, cbuf, counts, tlist, rlist, wA, wB, eA, eB, xb,
        out + (size_t)B_TOK * HID);
    pad_kernel<<<NEXP, 256, 0, stream>>>(counts, tlist, rlist);
    moe_gemm_kernel<<<dim3(HID / BN, B_TOK / BM, NEXP), 512, 0, stream>>>(
        xb, Wb, counts, tlist, rlist, out, y1, trash);
    combine_kernel<<<B_TOK, 256, 0, stream>>>(
        y1, expert_b, wA, wB, eA, eB, out);
}